// Round 9
// baseline (203.613 us; speedup 1.0000x reference)
//
#include <hip/hip_runtime.h>
#include <stdint.h>
#include <stddef.h>

typedef __attribute__((ext_vector_type(4))) float  f32x4;
typedef __attribute__((ext_vector_type(8))) short  s16x8;
typedef __attribute__((ext_vector_type(4))) float  float4v;
typedef __attribute__((ext_vector_type(4))) unsigned short u16x4;
typedef __attribute__((ext_vector_type(2))) unsigned int   u32x2;

#define DIM    1024
#define HEADS  16
#define HD     64
#define SEQ    2048
#define BATCH  2
#define TOKENS (BATCH * SEQ)   // 4096

// 0.125 (1/sqrt(64)) * log2(e): folded into Q so softmax uses exp2 directly
#define QSCALE 0.18033688011112042f

// ---------- helpers ----------
__device__ __forceinline__ unsigned short f2bf(float f) {
  union { float f; uint32_t u; } x; x.f = f;
  uint32_t r = x.u + 0x7fffu + ((x.u >> 16) & 1u);   // RNE
  return (unsigned short)(r >> 16);
}

__device__ __forceinline__ float fast_exp2(float x) {
#if __has_builtin(__builtin_amdgcn_exp2f)
  return __builtin_amdgcn_exp2f(x);
#else
  return exp2f(x);
#endif
}

// pack high-16s of two fp32 into one dword: (hi & 0xffff0000) | (lo >> 16)
__device__ __forceinline__ uint32_t pack_bf16_trunc(uint32_t lo, uint32_t hi) {
#if __has_builtin(__builtin_amdgcn_perm)
  return __builtin_amdgcn_perm(hi, lo, 0x07060302u);
#else
  return (hi & 0xffff0000u) | (lo >> 16);
#endif
}

// async global->LDS, 16 B per lane; lds dest = base + lane*16 (wave-uniform base)
__device__ __forceinline__ void stage16(const unsigned short* gp, unsigned short* lp) {
#if __has_builtin(__builtin_amdgcn_global_load_lds)
  __builtin_amdgcn_global_load_lds((const __attribute__((address_space(1))) void*)gp,
                                   (__attribute__((address_space(3))) void*)lp, 16, 0, 0);
#else
  *(s16x8*)(lp + (threadIdx.x & 63) * 8) = *(const s16x8*)gp;
#endif
}

// ---------- fused cast fp32 -> bf16 (x, W_qkv, W_out in one launch) ----------
#define N4_X  (TOKENS * DIM / 4)
#define N4_WQ (3 * DIM * DIM / 4)
#define N4_WO (DIM * DIM / 4)
__global__ __launch_bounds__(256) void mhsa_cast_all(const float* __restrict__ x,
    const float* __restrict__ wq, const float* __restrict__ wo,
    unsigned short* __restrict__ xb, unsigned short* __restrict__ wqb,
    unsigned short* __restrict__ wob) {
  int i = blockIdx.x * 256 + threadIdx.x;
  const float* src; unsigned short* dst; int off;
  if (i < N4_X)              { src = x;  dst = xb;  off = i; }
  else if (i < N4_X + N4_WQ) { src = wq; dst = wqb; off = i - N4_X; }
  else                       { src = wo; dst = wob; off = i - (N4_X + N4_WQ); }
  float4v f = ((const float4v*)src)[off];
  u16x4 o;
  o.x = f2bf(f.x); o.y = f2bf(f.y); o.z = f2bf(f.z); o.w = f2bf(f.w);
  ((u16x4*)dst)[off] = o;
}

// ================= GEMM core v3 =================
// BK=32, dbuf, 1 barrier/iter, XOR-swizzled 16B chunks, 3 blocks/CU.
// T1: XCD-chunked block swizzle -- co-locate blocks sharing an A-panel on one XCD.

// ---------- QKV GEMM (operand-swapped): C^T layout, packed epilogue ----------
__global__ __launch_bounds__(256, 3) void mhsa_gemm_qkv(const unsigned short* __restrict__ A,
    const unsigned short* __restrict__ Bw, const float* __restrict__ bias,
    unsigned short* __restrict__ qws, unsigned short* __restrict__ kws,
    unsigned short* __restrict__ vws) {
  __shared__ unsigned short As[2][128 * 32];
  __shared__ unsigned short Bs[2][128 * 32];
  const int t = threadIdx.x;
  const int w = t >> 6, l = t & 63;
  const int wm = w >> 1, wn = w & 1;
  // XCD swizzle: grid (24,32), 768 = 8 XCDs x 96. c = lin%8 -> XCD; each XCD gets
  // 4 complete row-panels (by' in {4c..4c+3}); all 24 col-blocks of a panel share it.
  const int lin = blockIdx.y * 24 + blockIdx.x;
  const int xc = lin & 7, j = lin >> 3;               // j in [0,96)
  const int rowBase = (xc * 4 + j / 24) * 128;        // tokens
  const int colBase = (j % 24) * 128;                 // e
  const int fr = l & 15, q4 = l >> 4, ln = l & 15;
  const int srow = l >> 2;                       // staging row within slab
  const int scol = ((l & 3) ^ (srow & 3)) * 8;   // swizzled global column

  f32x4 zero = {0.f, 0.f, 0.f, 0.f};
  f32x4 acc[4][4];   // [a=e-tile][b=token-tile]
  #pragma unroll
  for (int a = 0; a < 4; ++a)
    #pragma unroll
    for (int b = 0; b < 4; ++b) acc[a][b] = zero;

  #pragma unroll
  for (int it = 0; it < 2; ++it) {
    const int c = w * 2 + it;
    stage16(A  + (size_t)(rowBase + c * 16 + srow) * DIM + scol, &As[0][c * 512]);
    stage16(Bw + (size_t)(colBase + c * 16 + srow) * DIM + scol, &Bs[0][c * 512]);
  }
  __syncthreads();

  for (int kt = 0; kt < DIM / 32; ++kt) {
    const int cur = kt & 1, nxt = cur ^ 1;
    if (kt + 1 < DIM / 32) {
      const int k1 = (kt + 1) * 32;
      #pragma unroll
      for (int it = 0; it < 2; ++it) {
        const int c = w * 2 + it;
        stage16(A  + (size_t)(rowBase + c * 16 + srow) * DIM + k1 + scol, &As[nxt][c * 512]);
        stage16(Bw + (size_t)(colBase + c * 16 + srow) * DIM + k1 + scol, &Bs[nxt][c * 512]);
      }
    }
    s16x8 xf[4], wf[4];
    #pragma unroll
    for (int b = 0; b < 4; ++b)
      xf[b] = *(const s16x8*)&As[cur][(wm * 64 + b * 16 + fr) * 32 + ((q4 ^ (fr & 3)) * 8)];
    #pragma unroll
    for (int a = 0; a < 4; ++a)
      wf[a] = *(const s16x8*)&Bs[cur][(wn * 64 + a * 16 + fr) * 32 + ((q4 ^ (fr & 3)) * 8)];
    #pragma unroll
    for (int a = 0; a < 4; ++a)
      #pragma unroll
      for (int b = 0; b < 4; ++b)
        acc[a][b] = __builtin_amdgcn_mfma_f32_16x16x32_bf16(wf[a], xf[b], acc[a][b], 0, 0, 0);
    __syncthreads();
  }

  const int which = colBase >> 10;   // 0=Q 1=K 2=V (block never straddles)
  const float sc = (which == 0) ? QSCALE : 1.0f;
  unsigned short* dst = (which == 0) ? qws : ((which == 1) ? kws : vws);

  #pragma unroll
  for (int a = 0; a < 4; ++a) {
    const int e0 = colBase + wn * 64 + a * 16 + q4 * 4;  // 4-aligned, 4 consecutive e
    const float4v bs4 = *(const float4v*)&bias[e0];
    const int rr0 = e0 & 1023;
    const int h = rr0 >> 6, d0 = rr0 & 63;               // d0..d0+3 within one head
    #pragma unroll
    for (int b = 0; b < 4; ++b) {
      const int tok = rowBase + wm * 64 + b * 16 + ln;
      const int bb = tok >> 11, n = tok & 2047;
      if (which != 2) {
        u16x4 pk;
        #pragma unroll
        for (int r = 0; r < 4; ++r) pk[r] = f2bf((acc[a][b][r] + bs4[r]) * sc);
        *(u16x4*)&dst[(((size_t)(bb * HEADS + h)) * SEQ + n) * HD + d0] = pk;
      } else {
        #pragma unroll
        for (int r = 0; r < 4; ++r)
          dst[(((size_t)(bb * HEADS + h)) * HD + d0 + r) * SEQ + n] =
              f2bf(acc[a][b][r] + bs4[r]);
      }
    }
  }
}

// ---------- Output GEMM (operand-swapped): 64x128 tiles, float4 epilogue ----------
__global__ __launch_bounds__(256, 3) void mhsa_gemm_out(const unsigned short* __restrict__ A,
    const unsigned short* __restrict__ Bw, const float* __restrict__ bias,
    float* __restrict__ out) {
  __shared__ unsigned short As[2][64 * 32];
  __shared__ unsigned short Bs[2][128 * 32];
  const int t = threadIdx.x;
  const int w = t >> 6, l = t & 63;
  const int wm = w >> 1, wn = w & 1;
  // XCD swizzle: grid (8,64), 512 = 8 x 64; each XCD gets 8 row-panels.
  const int lin = blockIdx.y * 8 + blockIdx.x;
  const int xc = lin & 7, j = lin >> 3;               // j in [0,64)
  const int rowBase = (xc * 8 + (j >> 3)) * 64;       // tokens
  const int colBase = (j & 7) * 128;                  // e
  const int fr = l & 15, q4 = l >> 4, ln = l & 15;
  const int srow = l >> 2;
  const int scol = ((l & 3) ^ (srow & 3)) * 8;

  f32x4 zero = {0.f, 0.f, 0.f, 0.f};
  f32x4 acc[4][2];   // [a=e-tile][b=token-tile]
  #pragma unroll
  for (int a = 0; a < 4; ++a)
    #pragma unroll
    for (int b = 0; b < 2; ++b) acc[a][b] = zero;

  #pragma unroll
  for (int it = 0; it < 3; ++it) {
    const int s = w * 3 + it;
    if (s < 4) stage16(A  + (size_t)(rowBase + s * 16 + srow) * DIM + scol, &As[0][s * 512]);
    else       stage16(Bw + (size_t)(colBase + (s - 4) * 16 + srow) * DIM + scol, &Bs[0][(s - 4) * 512]);
  }
  __syncthreads();

  for (int kt = 0; kt < DIM / 32; ++kt) {
    const int cur = kt & 1, nxt = cur ^ 1;
    if (kt + 1 < DIM / 32) {
      const int k1 = (kt + 1) * 32;
      #pragma unroll
      for (int it = 0; it < 3; ++it) {
        const int s = w * 3 + it;
        if (s < 4) stage16(A  + (size_t)(rowBase + s * 16 + srow) * DIM + k1 + scol, &As[nxt][s * 512]);
        else       stage16(Bw + (size_t)(colBase + (s - 4) * 16 + srow) * DIM + k1 + scol, &Bs[nxt][(s - 4) * 512]);
      }
    }
    s16x8 xf[2], wf[4];
    #pragma unroll
    for (int b = 0; b < 2; ++b)
      xf[b] = *(const s16x8*)&As[cur][(wm * 32 + b * 16 + fr) * 32 + ((q4 ^ (fr & 3)) * 8)];
    #pragma unroll
    for (int a = 0; a < 4; ++a)
      wf[a] = *(const s16x8*)&Bs[cur][(wn * 64 + a * 16 + fr) * 32 + ((q4 ^ (fr & 3)) * 8)];
    #pragma unroll
    for (int a = 0; a < 4; ++a)
      #pragma unroll
      for (int b = 0; b < 2; ++b)
        acc[a][b] = __builtin_amdgcn_mfma_f32_16x16x32_bf16(wf[a], xf[b], acc[a][b], 0, 0, 0);
    __syncthreads();
  }

  #pragma unroll
  for (int a = 0; a < 4; ++a) {
    const int e0 = colBase + wn * 64 + a * 16 + q4 * 4;
    const float4v bs4 = *(const float4v*)&bias[e0];
    #pragma unroll
    for (int b = 0; b < 2; ++b) {
      const int tok = rowBase + wm * 32 + b * 16 + ln;
      float4v v;
      #pragma unroll
      for (int r = 0; r < 4; ++r) v[r] = acc[a][b][r] + bs4[r];
      *(float4v*)&out[(size_t)tok * DIM + e0] = v;
    }
  }
}

// ---------- Flash attention v15: v13 schedule, V fragments direct from global ----------
// 256 threads (4 waves x 32 q-rows), K staged in LDS (dbuf, 2-ahead), P via LDS
// round-trip, rowsum on the matrix pipe, setprio, XCD-aware bh swizzle.
// CHANGE vs v13: the Vs LDS buffer is DELETED. The PV B-fragment
// V^T[d=jd*16+ln][kv=jt*64 + (q4|4+q4)*8 ..+7] is contiguous in the global vt
// layout (lanes {l,l+16,l+32,l+48} form 64-B segments) and L2-resident (bh pinned
// to one XCD by the swizzle). The 8 bv loads are independent of the St MFMA chain,
// so they issue before it and their L2 latency is covered. Deletes 8 of 20 LDS
// frag reads per wave-iter, 2 staging DMAs/iter, and 16 KB LDS. Schedule, barriers,
// K path, P path, epilogue: byte-for-byte v13.
__global__ __launch_bounds__(256, 2) void mhsa_attn(const unsigned short* __restrict__ q,
    const unsigned short* __restrict__ k, const unsigned short* __restrict__ vt,
    unsigned short* __restrict__ o) {
  __shared__ unsigned short QPs[4 * 32 * 72];   // per-wave 2304: Q staged (2048) then P (32x72)
  __shared__ unsigned short Ks[2][64 * 64];     // dbuf K tile (staged 2 ahead)
  const int t = threadIdx.x, w = t >> 6, l = t & 63;
  const int q4 = l >> 4, ln = l & 15;
  // XCD swizzle: grid (16,32). lin = by*16+bx; XCD = lin%8 gets bh in {4c..4c+3}.
  const int lin = blockIdx.y * 16 + blockIdx.x;
  const int xc = lin & 7, m = lin >> 3;          // m in [0,64)
  const int bh = xc * 4 + (m >> 4);
  const int q0 = (m & 15) * 128;
  const unsigned short* qb  = q  + (size_t)bh * SEQ * HD;
  const unsigned short* kb  = k  + (size_t)bh * SEQ * HD;
  const unsigned short* vtb = vt + (size_t)bh * HD * SEQ;

  const int srow = l >> 3;
  const int scol = ((l & 7) ^ srow) * 8;

  unsigned short* Pw = &QPs[w * (32 * 72)];
  // per-lane V^T base: row d = (jd*16 + ln), cols jt*64 + q4*8 (+32 for bv1)
  const unsigned short* vLane = vtb + (size_t)ln * SEQ + q4 * 8;

  // bf16 1.0 x8 for the row-sum MFMA B operand
  const s16x8 vones = {(short)0x3F80, (short)0x3F80, (short)0x3F80, (short)0x3F80,
                       (short)0x3F80, (short)0x3F80, (short)0x3F80, (short)0x3F80};

  // prologue staging: Q (wave-local region), K_0, K_1
  #pragma unroll
  for (int it = 0; it < 4; ++it)
    stage16(qb + (size_t)(q0 + w * 32 + it * 8 + srow) * HD + scol, &Pw[it * 512]);
  #pragma unroll
  for (int it = 0; it < 2; ++it) {
    const int c = w + it * 4;
    stage16(kb  + (size_t)(c * 8 + srow) * HD + scol,        &Ks[0][c * 512]);
    stage16(kb  + (size_t)(64 + c * 8 + srow) * HD + scol,   &Ks[1][c * 512]);
  }
  __syncthreads();   // publishes Q + K_0 + K_1

  // hoist Q fragments; Pw region then reused for P
  s16x8 aq[2][2];
  #pragma unroll
  for (int i = 0; i < 2; ++i)
    #pragma unroll
    for (int kk = 0; kk < 2; ++kk)
      aq[i][kk] = *(const s16x8*)&Pw[(i * 16 + ln) * 64 + (((kk * 4 + q4) ^ (ln & 7)) * 8)];

  f32x4 zero = {0.f, 0.f, 0.f, 0.f};
  f32x4 accO[2][4];
  f32x4 accS[2] = {zero, zero};   // per-row sums of P (via MFMA with ones)
  #pragma unroll
  for (int i = 0; i < 2; ++i)
    #pragma unroll
    for (int jd = 0; jd < 4; ++jd) accO[i][jd] = zero;

  // prologue compute: S_0 from Ks[0], exp, write P_0
  {
    f32x4 St[4][2];
    #pragma unroll
    for (int jb = 0; jb < 4; ++jb)
      #pragma unroll
      for (int i = 0; i < 2; ++i) St[jb][i] = zero;
    __builtin_amdgcn_s_setprio(1);
    #pragma unroll
    for (int jb = 0; jb < 4; ++jb) {
      s16x8 ak0 = *(const s16x8*)&Ks[0][(jb * 16 + ln) * 64 + ((q4 ^ (ln & 7)) * 8)];
      s16x8 ak1 = *(const s16x8*)&Ks[0][(jb * 16 + ln) * 64 + (((4 + q4) ^ (ln & 7)) * 8)];
      #pragma unroll
      for (int i = 0; i < 2; ++i) {
        St[jb][i] = __builtin_amdgcn_mfma_f32_16x16x32_bf16(ak0, aq[i][0], St[jb][i], 0, 0, 0);
        St[jb][i] = __builtin_amdgcn_mfma_f32_16x16x32_bf16(ak1, aq[i][1], St[jb][i], 0, 0, 0);
      }
    }
    __builtin_amdgcn_s_setprio(0);
    #pragma unroll
    for (int i = 0; i < 2; ++i)
      #pragma unroll
      for (int jb = 0; jb < 4; ++jb) {
        uint32_t u0 = __float_as_uint(fast_exp2(St[jb][i][0]));
        uint32_t u1 = __float_as_uint(fast_exp2(St[jb][i][1]));
        uint32_t u2 = __float_as_uint(fast_exp2(St[jb][i][2]));
        uint32_t u3 = __float_as_uint(fast_exp2(St[jb][i][3]));
        u32x2 pk;
        pk.x = pack_bf16_trunc(u0, u1);
        pk.y = pack_bf16_trunc(u2, u3);
        *(u32x2*)&Pw[(i * 16 + ln) * 72 + jb * 16 + q4 * 4] = pk;
      }
  }
  __syncthreads();   // drains K_0 frag reads before loop iter 0 overwrites Ks[0]

  const int NT = SEQ / 64;   // 32
  for (int jt = 0; jt < NT; ++jt) {
    const int cur = jt & 1, nxt = cur ^ 1;
    // stage K_{jt+2} into slot cur (K_jt's reads drained at previous barrier)
    if (jt + 2 < NT) {
      const int j2 = (jt + 2) * 64;
      #pragma unroll
      for (int it = 0; it < 2; ++it) {
        const int c = w + it * 4;
        stage16(kb + (size_t)(j2 + c * 8 + srow) * HD + scol, &Ks[cur][c * 512]);
      }
    }

    // ---- stream A: PV_jt from P_jt (written last iter) and V_jt (global) ----
    s16x8 ap[2][2];
    #pragma unroll
    for (int i = 0; i < 2; ++i)
      #pragma unroll
      for (int kk = 0; kk < 2; ++kk)
        ap[i][kk] = *(const s16x8*)&Pw[(i * 16 + ln) * 72 + kk * 32 + q4 * 8];

    // row-sum MFMAs: accS[i] += P x ones (sums exactly the stored bf16 P values)
    __builtin_amdgcn_s_setprio(1);
    #pragma unroll
    for (int i = 0; i < 2; ++i) {
      accS[i] = __builtin_amdgcn_mfma_f32_16x16x32_bf16(ap[i][0], vones, accS[i], 0, 0, 0);
      accS[i] = __builtin_amdgcn_mfma_f32_16x16x32_bf16(ap[i][1], vones, accS[i], 0, 0, 0);
    }
    __builtin_amdgcn_s_setprio(0);

    // V fragments for this tile, straight from global (L2-hot, 64-B segments);
    // independent of the St chain below -> issue early, latency covered.
    s16x8 bv0[4], bv1[4];
    #pragma unroll
    for (int jd = 0; jd < 4; ++jd) {
      const unsigned short* vp = vLane + (size_t)jd * 16 * SEQ + jt * 64;
      bv0[jd] = *(const s16x8*)(vp);
      bv1[jd] = *(const s16x8*)(vp + 32);
    }

    // ---- stream B: S_{jt+1} from K_{jt+1} (slot nxt) ----
    if (jt + 1 < NT) {
      f32x4 St[4][2];
      #pragma unroll
      for (int jb = 0; jb < 4; ++jb)
        #pragma unroll
        for (int i = 0; i < 2; ++i) St[jb][i] = zero;
      __builtin_amdgcn_s_setprio(1);
      #pragma unroll
      for (int jb = 0; jb < 4; ++jb) {
        s16x8 ak0 = *(const s16x8*)&Ks[nxt][(jb * 16 + ln) * 64 + ((q4 ^ (ln & 7)) * 8)];
        s16x8 ak1 = *(const s16x8*)&Ks[nxt][(jb * 16 + ln) * 64 + (((4 + q4) ^ (ln & 7)) * 8)];
        #pragma unroll
        for (int i = 0; i < 2; ++i) {
          St[jb][i] = __builtin_amdgcn_mfma_f32_16x16x32_bf16(ak0, aq[i][0], St[jb][i], 0, 0, 0);
          St[jb][i] = __builtin_amdgcn_mfma_f32_16x16x32_bf16(ak1, aq[i][1], St[jb][i], 0, 0, 0);
        }
      }

      // PV_jt MFMAs (independent of St chain; fills MFMA pipe while exp runs)
      #pragma unroll
      for (int jd = 0; jd < 4; ++jd) {
        #pragma unroll
        for (int i = 0; i < 2; ++i) {
          accO[i][jd] = __builtin_amdgcn_mfma_f32_16x16x32_bf16(ap[i][0], bv0[jd], accO[i][jd], 0, 0, 0);
          accO[i][jd] = __builtin_amdgcn_mfma_f32_16x16x32_bf16(ap[i][1], bv1[jd], accO[i][jd], 0, 0, 0);
        }
      }
      __builtin_amdgcn_s_setprio(0);

      // exp -> pack -> write P_{jt+1} (anti-dep on ap reads keeps order vs Pw)
      #pragma unroll
      for (int i = 0; i < 2; ++i)
        #pragma unroll
        for (int jb = 0; jb < 4; ++jb) {
          uint32_t u0 = __float_as_uint(fast_exp2(St[jb][i][0]));
          uint32_t u1 = __float_as_uint(fast_exp2(St[jb][i][1]));
          uint32_t u2 = __float_as_uint(fast_exp2(St[jb][i][2]));
          uint32_t u3 = __float_as_uint(fast_exp2(St[jb][i][3]));
          u32x2 pk;
          pk.x = pack_bf16_trunc(u0, u1);
          pk.y = pack_bf16_trunc(u2, u3);
          *(u32x2*)&Pw[(i * 16 + ln) * 72 + jb * 16 + q4 * 4] = pk;
        }
    } else {
      // last iter: only PV
      __builtin_amdgcn_s_setprio(1);
      #pragma unroll
      for (int jd = 0; jd < 4; ++jd) {
        #pragma unroll
        for (int i = 0; i < 2; ++i) {
          accO[i][jd] = __builtin_amdgcn_mfma_f32_16x16x32_bf16(ap[i][0], bv0[jd], accO[i][jd], 0, 0, 0);
          accO[i][jd] = __builtin_amdgcn_mfma_f32_16x16x32_bf16(ap[i][1], bv1[jd], accO[i][jd], 0, 0, 0);
        }
      }
      __builtin_amdgcn_s_setprio(0);
    }

    __syncthreads();   // publishes K staging; drains cur-slot reads before reuse
  }

  // epilogue: accS[i][r] already holds the full row sum for q-row q4*4+r
  // (same D-layout row indexing as accO) -> normalize + store, no shuffles
  const int b = bh >> 4, h = bh & 15;
  #pragma unroll
  for (int i = 0; i < 2; ++i) {
    #pragma unroll
    for (int r = 0; r < 4; ++r) {
      const float invr = 1.f / accS[i][r];
      const int row = q0 + w * 32 + i * 16 + q4 * 4 + r;
      #pragma unroll
      for (int jd = 0; jd < 4; ++jd)
        o[((size_t)(b * SEQ + row)) * DIM + h * HD + jd * 16 + ln] = f2bf(accO[i][jd][r] * invr);
    }
  }
}

// ---------- launch ----------
extern "C" void kernel_launch(void* const* d_in, const int* in_sizes, int n_in,
                              void* d_out, int out_size, void* d_ws, size_t ws_size,
                              hipStream_t stream) {
  const float* x     = (const float*)d_in[0];   // [2,2048,1024]
  const float* Wqkv  = (const float*)d_in[1];   // [3072,1024]
  const float* bqkv  = (const float*)d_in[2];   // [3072]
  const float* Wout  = (const float*)d_in[3];   // [1024,1024]
  const float* bout  = (const float*)d_in[4];   // [1024]
  float* out = (float*)d_out;

  unsigned short* ws = (unsigned short*)d_ws;
  unsigned short* x_bf    = ws;
  unsigned short* wqkv_bf = x_bf    + (size_t)TOKENS * DIM;
  unsigned short* wout_bf = wqkv_bf + (size_t)3 * DIM * DIM;
  unsigned short* q_ws    = wout_bf + (size_t)DIM * DIM;
  unsigned short* k_ws    = q_ws    + (size_t)TOKENS * DIM;
  unsigned short* v_ws    = k_ws    + (size_t)TOKENS * DIM;    // transposed [bh][d][n]
  unsigned short* ao_ws   = v_ws    + (size_t)TOKENS * DIM;

  // fused cast (one launch)
  {
    const int n4 = N4_X + N4_WQ + N4_WO;   // 2,097,152 -> 8192 blocks
    mhsa_cast_all<<<n4 / 256, 256, 0, stream>>>(x, Wqkv, Wout, x_bf, wqkv_bf, wout_bf);
  }

  // QKV projection + scatter (V transposed, Q pre-scaled)
  {
    dim3 grid(3 * DIM / 128, TOKENS / 128);   // (24, 32) = 768 blocks = 3/CU, one round
    mhsa_gemm_qkv<<<grid, 256, 0, stream>>>(x_bf, wqkv_bf, bqkv, q_ws, k_ws, v_ws);
  }

  // fused attention
  {
    dim3 grid(SEQ / 128, BATCH * HEADS);      // (16, 32), 256 threads
    mhsa_attn<<<grid, 256, 0, stream>>>(q_ws, k_ws, v_ws, ao_ws);
  }

  // output projection
  {
    dim3 grid(DIM / 128, TOKENS / 64);        // (8, 64) = 512 blocks
    mhsa_gemm_out<<<grid, 256, 0, stream>>>(ao_ws, wout_bf, bout, out);
  }
}

// Round 11
// 181.558 us; speedup vs baseline: 1.1215x; 1.1215x over previous
//
#include <hip/hip_runtime.h>
#include <stdint.h>
#include <stddef.h>

typedef __attribute__((ext_vector_type(4))) float  f32x4;
typedef __attribute__((ext_vector_type(8))) short  s16x8;
typedef __attribute__((ext_vector_type(4))) float  float4v;
typedef __attribute__((ext_vector_type(4))) unsigned short u16x4;
typedef __attribute__((ext_vector_type(2))) unsigned int   u32x2;

#define DIM    1024
#define HEADS  16
#define HD     64
#define SEQ    2048
#define BATCH  2
#define TOKENS (BATCH * SEQ)   // 4096

// 0.125 (1/sqrt(64)) * log2(e): folded into Q so softmax uses exp2 directly
#define QSCALE 0.18033688011112042f

// ---------- helpers ----------
__device__ __forceinline__ unsigned short f2bf(float f) {
  union { float f; uint32_t u; } x; x.f = f;
  uint32_t r = x.u + 0x7fffu + ((x.u >> 16) & 1u);   // RNE
  return (unsigned short)(r >> 16);
}

__device__ __forceinline__ float fast_exp2(float x) {
#if __has_builtin(__builtin_amdgcn_exp2f)
  return __builtin_amdgcn_exp2f(x);
#else
  return exp2f(x);
#endif
}

// pack high-16s of two fp32 into one dword: (hi & 0xffff0000) | (lo >> 16)
__device__ __forceinline__ uint32_t pack_bf16_trunc(uint32_t lo, uint32_t hi) {
#if __has_builtin(__builtin_amdgcn_perm)
  return __builtin_amdgcn_perm(hi, lo, 0x07060302u);
#else
  return (hi & 0xffff0000u) | (lo >> 16);
#endif
}

// async global->LDS, 16 B per lane; lds dest = base + lane*16 (wave-uniform base)
__device__ __forceinline__ void stage16(const unsigned short* gp, unsigned short* lp) {
#if __has_builtin(__builtin_amdgcn_global_load_lds)
  __builtin_amdgcn_global_load_lds((const __attribute__((address_space(1))) void*)gp,
                                   (__attribute__((address_space(3))) void*)lp, 16, 0, 0);
#else
  *(s16x8*)(lp + (threadIdx.x & 63) * 8) = *(const s16x8*)gp;
#endif
}

// ---------- fused cast fp32 -> bf16 (x, W_qkv, W_out in one launch) ----------
#define N4_X  (TOKENS * DIM / 4)
#define N4_WQ (3 * DIM * DIM / 4)
#define N4_WO (DIM * DIM / 4)
__global__ __launch_bounds__(256) void mhsa_cast_all(const float* __restrict__ x,
    const float* __restrict__ wq, const float* __restrict__ wo,
    unsigned short* __restrict__ xb, unsigned short* __restrict__ wqb,
    unsigned short* __restrict__ wob) {
  int i = blockIdx.x * 256 + threadIdx.x;
  const float* src; unsigned short* dst; int off;
  if (i < N4_X)              { src = x;  dst = xb;  off = i; }
  else if (i < N4_X + N4_WQ) { src = wq; dst = wqb; off = i - N4_X; }
  else                       { src = wo; dst = wob; off = i - (N4_X + N4_WQ); }
  float4v f = ((const float4v*)src)[off];
  u16x4 o;
  o.x = f2bf(f.x); o.y = f2bf(f.y); o.z = f2bf(f.z); o.w = f2bf(f.w);
  ((u16x4*)dst)[off] = o;
}

// ================= GEMM core v3 =================
// BK=32, dbuf, 1 barrier/iter, XOR-swizzled 16B chunks, 3 blocks/CU.
// T1: XCD-chunked block swizzle -- co-locate blocks sharing an A-panel on one XCD.

// ---------- QKV GEMM (operand-swapped): C^T layout, packed epilogue ----------
__global__ __launch_bounds__(256, 3) void mhsa_gemm_qkv(const unsigned short* __restrict__ A,
    const unsigned short* __restrict__ Bw, const float* __restrict__ bias,
    unsigned short* __restrict__ qws, unsigned short* __restrict__ kws,
    unsigned short* __restrict__ vws) {
  __shared__ unsigned short As[2][128 * 32];
  __shared__ unsigned short Bs[2][128 * 32];
  const int t = threadIdx.x;
  const int w = t >> 6, l = t & 63;
  const int wm = w >> 1, wn = w & 1;
  // XCD swizzle: grid (24,32), 768 = 8 XCDs x 96. c = lin%8 -> XCD; each XCD gets
  // 4 complete row-panels (by' in {4c..4c+3}); all 24 col-blocks of a panel share it.
  const int lin = blockIdx.y * 24 + blockIdx.x;
  const int xc = lin & 7, j = lin >> 3;               // j in [0,96)
  const int rowBase = (xc * 4 + j / 24) * 128;        // tokens
  const int colBase = (j % 24) * 128;                 // e
  const int fr = l & 15, q4 = l >> 4, ln = l & 15;
  const int srow = l >> 2;                       // staging row within slab
  const int scol = ((l & 3) ^ (srow & 3)) * 8;   // swizzled global column

  f32x4 zero = {0.f, 0.f, 0.f, 0.f};
  f32x4 acc[4][4];   // [a=e-tile][b=token-tile]
  #pragma unroll
  for (int a = 0; a < 4; ++a)
    #pragma unroll
    for (int b = 0; b < 4; ++b) acc[a][b] = zero;

  #pragma unroll
  for (int it = 0; it < 2; ++it) {
    const int c = w * 2 + it;
    stage16(A  + (size_t)(rowBase + c * 16 + srow) * DIM + scol, &As[0][c * 512]);
    stage16(Bw + (size_t)(colBase + c * 16 + srow) * DIM + scol, &Bs[0][c * 512]);
  }
  __syncthreads();

  for (int kt = 0; kt < DIM / 32; ++kt) {
    const int cur = kt & 1, nxt = cur ^ 1;
    if (kt + 1 < DIM / 32) {
      const int k1 = (kt + 1) * 32;
      #pragma unroll
      for (int it = 0; it < 2; ++it) {
        const int c = w * 2 + it;
        stage16(A  + (size_t)(rowBase + c * 16 + srow) * DIM + k1 + scol, &As[nxt][c * 512]);
        stage16(Bw + (size_t)(colBase + c * 16 + srow) * DIM + k1 + scol, &Bs[nxt][c * 512]);
      }
    }
    s16x8 xf[4], wf[4];
    #pragma unroll
    for (int b = 0; b < 4; ++b)
      xf[b] = *(const s16x8*)&As[cur][(wm * 64 + b * 16 + fr) * 32 + ((q4 ^ (fr & 3)) * 8)];
    #pragma unroll
    for (int a = 0; a < 4; ++a)
      wf[a] = *(const s16x8*)&Bs[cur][(wn * 64 + a * 16 + fr) * 32 + ((q4 ^ (fr & 3)) * 8)];
    #pragma unroll
    for (int a = 0; a < 4; ++a)
      #pragma unroll
      for (int b = 0; b < 4; ++b)
        acc[a][b] = __builtin_amdgcn_mfma_f32_16x16x32_bf16(wf[a], xf[b], acc[a][b], 0, 0, 0);
    __syncthreads();
  }

  const int which = colBase >> 10;   // 0=Q 1=K 2=V (block never straddles)
  const float sc = (which == 0) ? QSCALE : 1.0f;
  unsigned short* dst = (which == 0) ? qws : ((which == 1) ? kws : vws);

  #pragma unroll
  for (int a = 0; a < 4; ++a) {
    const int e0 = colBase + wn * 64 + a * 16 + q4 * 4;  // 4-aligned, 4 consecutive e
    const float4v bs4 = *(const float4v*)&bias[e0];
    const int rr0 = e0 & 1023;
    const int h = rr0 >> 6, d0 = rr0 & 63;               // d0..d0+3 within one head
    #pragma unroll
    for (int b = 0; b < 4; ++b) {
      const int tok = rowBase + wm * 64 + b * 16 + ln;
      const int bb = tok >> 11, n = tok & 2047;
      if (which != 2) {
        u16x4 pk;
        #pragma unroll
        for (int r = 0; r < 4; ++r) pk[r] = f2bf((acc[a][b][r] + bs4[r]) * sc);
        *(u16x4*)&dst[(((size_t)(bb * HEADS + h)) * SEQ + n) * HD + d0] = pk;
      } else {
        #pragma unroll
        for (int r = 0; r < 4; ++r)
          dst[(((size_t)(bb * HEADS + h)) * HD + d0 + r) * SEQ + n] =
              f2bf(acc[a][b][r] + bs4[r]);
      }
    }
  }
}

// ---------- Output GEMM (operand-swapped): 64x128 tiles, float4 epilogue ----------
__global__ __launch_bounds__(256, 3) void mhsa_gemm_out(const unsigned short* __restrict__ A,
    const unsigned short* __restrict__ Bw, const float* __restrict__ bias,
    float* __restrict__ out) {
  __shared__ unsigned short As[2][64 * 32];
  __shared__ unsigned short Bs[2][128 * 32];
  const int t = threadIdx.x;
  const int w = t >> 6, l = t & 63;
  const int wm = w >> 1, wn = w & 1;
  // XCD swizzle: grid (8,64), 512 = 8 x 64; each XCD gets 8 row-panels.
  const int lin = blockIdx.y * 8 + blockIdx.x;
  const int xc = lin & 7, j = lin >> 3;               // j in [0,64)
  const int rowBase = (xc * 8 + (j >> 3)) * 64;       // tokens
  const int colBase = (j & 7) * 128;                  // e
  const int fr = l & 15, q4 = l >> 4, ln = l & 15;
  const int srow = l >> 2;
  const int scol = ((l & 3) ^ (srow & 3)) * 8;

  f32x4 zero = {0.f, 0.f, 0.f, 0.f};
  f32x4 acc[4][2];   // [a=e-tile][b=token-tile]
  #pragma unroll
  for (int a = 0; a < 4; ++a)
    #pragma unroll
    for (int b = 0; b < 2; ++b) acc[a][b] = zero;

  #pragma unroll
  for (int it = 0; it < 3; ++it) {
    const int s = w * 3 + it;
    if (s < 4) stage16(A  + (size_t)(rowBase + s * 16 + srow) * DIM + scol, &As[0][s * 512]);
    else       stage16(Bw + (size_t)(colBase + (s - 4) * 16 + srow) * DIM + scol, &Bs[0][(s - 4) * 512]);
  }
  __syncthreads();

  for (int kt = 0; kt < DIM / 32; ++kt) {
    const int cur = kt & 1, nxt = cur ^ 1;
    if (kt + 1 < DIM / 32) {
      const int k1 = (kt + 1) * 32;
      #pragma unroll
      for (int it = 0; it < 3; ++it) {
        const int s = w * 3 + it;
        if (s < 4) stage16(A  + (size_t)(rowBase + s * 16 + srow) * DIM + k1 + scol, &As[nxt][s * 512]);
        else       stage16(Bw + (size_t)(colBase + (s - 4) * 16 + srow) * DIM + k1 + scol, &Bs[nxt][(s - 4) * 512]);
      }
    }
    s16x8 xf[2], wf[4];
    #pragma unroll
    for (int b = 0; b < 2; ++b)
      xf[b] = *(const s16x8*)&As[cur][(wm * 32 + b * 16 + fr) * 32 + ((q4 ^ (fr & 3)) * 8)];
    #pragma unroll
    for (int a = 0; a < 4; ++a)
      wf[a] = *(const s16x8*)&Bs[cur][(wn * 64 + a * 16 + fr) * 32 + ((q4 ^ (fr & 3)) * 8)];
    #pragma unroll
    for (int a = 0; a < 4; ++a)
      #pragma unroll
      for (int b = 0; b < 2; ++b)
        acc[a][b] = __builtin_amdgcn_mfma_f32_16x16x32_bf16(wf[a], xf[b], acc[a][b], 0, 0, 0);
    __syncthreads();
  }

  #pragma unroll
  for (int a = 0; a < 4; ++a) {
    const int e0 = colBase + wn * 64 + a * 16 + q4 * 4;
    const float4v bs4 = *(const float4v*)&bias[e0];
    #pragma unroll
    for (int b = 0; b < 2; ++b) {
      const int tok = rowBase + wm * 32 + b * 16 + ln;
      float4v v;
      #pragma unroll
      for (int r = 0; r < 4; ++r) v[r] = acc[a][b][r] + bs4[r];
      *(float4v*)&out[(size_t)tok * DIM + e0] = v;
    }
  }
}

// ---------- Flash attention v13: v7 schedule + XCD-aware bh swizzle ----------
// 256 threads (4 waves x 32 q-rows), K/V tiles 64, XOR-swizzled staging, P via LDS
// round-trip, rowsum on the matrix pipe (P x ones), setprio around MFMA clusters.
// T1: blocks remapped so all 16 q-tiles of one bh land on ONE XCD (K/V 512KB
// L2-resident per bh; 4 bh = 2MB per XCD L2). c=lin%8 picks XCD; bh = c*4 + (m>>4).
// Session verdict: structural departures (reg-K/V, counted vmcnt, 32x32 in-reg P,
// 8-wave, V-from-global) all lost to this schedule. This is the proven optimum.
__global__ __launch_bounds__(256, 2) void mhsa_attn(const unsigned short* __restrict__ q,
    const unsigned short* __restrict__ k, const unsigned short* __restrict__ vt,
    unsigned short* __restrict__ o) {
  __shared__ unsigned short QPs[4 * 32 * 72];   // per-wave 2304: Q staged (2048) then P (32x72)
  __shared__ unsigned short Ks[2][64 * 64];     // dbuf K tile (staged 2 ahead)
  __shared__ unsigned short Vs[2][64 * 64];     // dbuf V^T tile (staged 1 ahead)
  const int t = threadIdx.x, w = t >> 6, l = t & 63;
  const int q4 = l >> 4, ln = l & 15;
  // XCD swizzle: grid (16,32). lin = by*16+bx; XCD = lin%8 gets bh in {4c..4c+3}.
  const int lin = blockIdx.y * 16 + blockIdx.x;
  const int xc = lin & 7, m = lin >> 3;          // m in [0,64)
  const int bh = xc * 4 + (m >> 4);
  const int q0 = (m & 15) * 128;
  const unsigned short* qb  = q  + (size_t)bh * SEQ * HD;
  const unsigned short* kb  = k  + (size_t)bh * SEQ * HD;
  const unsigned short* vtb = vt + (size_t)bh * HD * SEQ;

  const int srow = l >> 3;
  const int scol = ((l & 7) ^ srow) * 8;

  unsigned short* Pw = &QPs[w * (32 * 72)];

  // bf16 1.0 x8 for the row-sum MFMA B operand
  const s16x8 vones = {(short)0x3F80, (short)0x3F80, (short)0x3F80, (short)0x3F80,
                       (short)0x3F80, (short)0x3F80, (short)0x3F80, (short)0x3F80};

  // prologue staging: Q (wave-local region), K_0, V_0, K_1
  #pragma unroll
  for (int it = 0; it < 4; ++it)
    stage16(qb + (size_t)(q0 + w * 32 + it * 8 + srow) * HD + scol, &Pw[it * 512]);
  #pragma unroll
  for (int it = 0; it < 2; ++it) {
    const int c = w + it * 4;
    stage16(kb  + (size_t)(c * 8 + srow) * HD + scol,        &Ks[0][c * 512]);
    stage16(vtb + (size_t)(c * 8 + srow) * SEQ + scol,       &Vs[0][c * 512]);
    stage16(kb  + (size_t)(64 + c * 8 + srow) * HD + scol,   &Ks[1][c * 512]);
  }
  __syncthreads();   // publishes Q + K_0 + V_0 + K_1

  // hoist Q fragments; Pw region then reused for P
  s16x8 aq[2][2];
  #pragma unroll
  for (int i = 0; i < 2; ++i)
    #pragma unroll
    for (int kk = 0; kk < 2; ++kk)
      aq[i][kk] = *(const s16x8*)&Pw[(i * 16 + ln) * 64 + (((kk * 4 + q4) ^ (ln & 7)) * 8)];

  f32x4 zero = {0.f, 0.f, 0.f, 0.f};
  f32x4 accO[2][4];
  f32x4 accS[2] = {zero, zero};   // per-row sums of P (via MFMA with ones)
  #pragma unroll
  for (int i = 0; i < 2; ++i)
    #pragma unroll
    for (int jd = 0; jd < 4; ++jd) accO[i][jd] = zero;

  // prologue compute: S_0 from Ks[0], exp, write P_0
  {
    f32x4 St[4][2];
    #pragma unroll
    for (int jb = 0; jb < 4; ++jb)
      #pragma unroll
      for (int i = 0; i < 2; ++i) St[jb][i] = zero;
    __builtin_amdgcn_s_setprio(1);
    #pragma unroll
    for (int jb = 0; jb < 4; ++jb) {
      s16x8 ak0 = *(const s16x8*)&Ks[0][(jb * 16 + ln) * 64 + ((q4 ^ (ln & 7)) * 8)];
      s16x8 ak1 = *(const s16x8*)&Ks[0][(jb * 16 + ln) * 64 + (((4 + q4) ^ (ln & 7)) * 8)];
      #pragma unroll
      for (int i = 0; i < 2; ++i) {
        St[jb][i] = __builtin_amdgcn_mfma_f32_16x16x32_bf16(ak0, aq[i][0], St[jb][i], 0, 0, 0);
        St[jb][i] = __builtin_amdgcn_mfma_f32_16x16x32_bf16(ak1, aq[i][1], St[jb][i], 0, 0, 0);
      }
    }
    __builtin_amdgcn_s_setprio(0);
    #pragma unroll
    for (int i = 0; i < 2; ++i)
      #pragma unroll
      for (int jb = 0; jb < 4; ++jb) {
        uint32_t u0 = __float_as_uint(fast_exp2(St[jb][i][0]));
        uint32_t u1 = __float_as_uint(fast_exp2(St[jb][i][1]));
        uint32_t u2 = __float_as_uint(fast_exp2(St[jb][i][2]));
        uint32_t u3 = __float_as_uint(fast_exp2(St[jb][i][3]));
        u32x2 pk;
        pk.x = pack_bf16_trunc(u0, u1);
        pk.y = pack_bf16_trunc(u2, u3);
        *(u32x2*)&Pw[(i * 16 + ln) * 72 + jb * 16 + q4 * 4] = pk;
      }
  }
  __syncthreads();   // drains K_0 frag reads before loop iter 0 overwrites Ks[0]

  const int NT = SEQ / 64;   // 32
  for (int jt = 0; jt < NT; ++jt) {
    const int cur = jt & 1, nxt = cur ^ 1;
    // stage K_{jt+2} into slot cur (K_jt's reads drained at previous barrier);
    // stage V_{jt+1} into slot nxt (V_jt being read from slot cur)
    if (jt + 2 < NT) {
      const int j2 = (jt + 2) * 64;
      #pragma unroll
      for (int it = 0; it < 2; ++it) {
        const int c = w + it * 4;
        stage16(kb + (size_t)(j2 + c * 8 + srow) * HD + scol, &Ks[cur][c * 512]);
      }
    }
    if (jt + 1 < NT) {
      const int j1 = (jt + 1) * 64;
      #pragma unroll
      for (int it = 0; it < 2; ++it) {
        const int c = w + it * 4;
        stage16(vtb + (size_t)(c * 8 + srow) * SEQ + j1 + scol, &Vs[nxt][c * 512]);
      }
    }

    // ---- stream A: PV_jt from P_jt (written last iter) and V_jt ----
    s16x8 ap[2][2];
    #pragma unroll
    for (int i = 0; i < 2; ++i)
      #pragma unroll
      for (int kk = 0; kk < 2; ++kk)
        ap[i][kk] = *(const s16x8*)&Pw[(i * 16 + ln) * 72 + kk * 32 + q4 * 8];

    // row-sum MFMAs: accS[i] += P x ones (sums exactly the stored bf16 P values)
    __builtin_amdgcn_s_setprio(1);
    #pragma unroll
    for (int i = 0; i < 2; ++i) {
      accS[i] = __builtin_amdgcn_mfma_f32_16x16x32_bf16(ap[i][0], vones, accS[i], 0, 0, 0);
      accS[i] = __builtin_amdgcn_mfma_f32_16x16x32_bf16(ap[i][1], vones, accS[i], 0, 0, 0);
    }
    __builtin_amdgcn_s_setprio(0);

    // ---- stream B: S_{jt+1} from K_{jt+1} (slot nxt) ----
    if (jt + 1 < NT) {
      f32x4 St[4][2];
      #pragma unroll
      for (int jb = 0; jb < 4; ++jb)
        #pragma unroll
        for (int i = 0; i < 2; ++i) St[jb][i] = zero;
      __builtin_amdgcn_s_setprio(1);
      #pragma unroll
      for (int jb = 0; jb < 4; ++jb) {
        s16x8 ak0 = *(const s16x8*)&Ks[nxt][(jb * 16 + ln) * 64 + ((q4 ^ (ln & 7)) * 8)];
        s16x8 ak1 = *(const s16x8*)&Ks[nxt][(jb * 16 + ln) * 64 + (((4 + q4) ^ (ln & 7)) * 8)];
        #pragma unroll
        for (int i = 0; i < 2; ++i) {
          St[jb][i] = __builtin_amdgcn_mfma_f32_16x16x32_bf16(ak0, aq[i][0], St[jb][i], 0, 0, 0);
          St[jb][i] = __builtin_amdgcn_mfma_f32_16x16x32_bf16(ak1, aq[i][1], St[jb][i], 0, 0, 0);
        }
      }

      // PV_jt MFMAs (independent of St chain; fills MFMA pipe while exp runs)
      #pragma unroll
      for (int jd = 0; jd < 4; ++jd) {
        s16x8 bv0 = *(const s16x8*)&Vs[cur][(jd * 16 + ln) * 64 + ((q4 ^ (ln & 7)) * 8)];
        s16x8 bv1 = *(const s16x8*)&Vs[cur][(jd * 16 + ln) * 64 + (((4 + q4) ^ (ln & 7)) * 8)];
        #pragma unroll
        for (int i = 0; i < 2; ++i) {
          accO[i][jd] = __builtin_amdgcn_mfma_f32_16x16x32_bf16(ap[i][0], bv0, accO[i][jd], 0, 0, 0);
          accO[i][jd] = __builtin_amdgcn_mfma_f32_16x16x32_bf16(ap[i][1], bv1, accO[i][jd], 0, 0, 0);
        }
      }
      __builtin_amdgcn_s_setprio(0);

      // exp -> pack -> write P_{jt+1} (anti-dep on ap reads keeps order vs Pw)
      #pragma unroll
      for (int i = 0; i < 2; ++i)
        #pragma unroll
        for (int jb = 0; jb < 4; ++jb) {
          uint32_t u0 = __float_as_uint(fast_exp2(St[jb][i][0]));
          uint32_t u1 = __float_as_uint(fast_exp2(St[jb][i][1]));
          uint32_t u2 = __float_as_uint(fast_exp2(St[jb][i][2]));
          uint32_t u3 = __float_as_uint(fast_exp2(St[jb][i][3]));
          u32x2 pk;
          pk.x = pack_bf16_trunc(u0, u1);
          pk.y = pack_bf16_trunc(u2, u3);
          *(u32x2*)&Pw[(i * 16 + ln) * 72 + jb * 16 + q4 * 4] = pk;
        }
    } else {
      // last iter: only PV
      __builtin_amdgcn_s_setprio(1);
      #pragma unroll
      for (int jd = 0; jd < 4; ++jd) {
        s16x8 bv0 = *(const s16x8*)&Vs[cur][(jd * 16 + ln) * 64 + ((q4 ^ (ln & 7)) * 8)];
        s16x8 bv1 = *(const s16x8*)&Vs[cur][(jd * 16 + ln) * 64 + (((4 + q4) ^ (ln & 7)) * 8)];
        #pragma unroll
        for (int i = 0; i < 2; ++i) {
          accO[i][jd] = __builtin_amdgcn_mfma_f32_16x16x32_bf16(ap[i][0], bv0, accO[i][jd], 0, 0, 0);
          accO[i][jd] = __builtin_amdgcn_mfma_f32_16x16x32_bf16(ap[i][1], bv1, accO[i][jd], 0, 0, 0);
        }
      }
      __builtin_amdgcn_s_setprio(0);
    }

    __syncthreads();   // publishes staging; drains cur-slot reads before reuse
  }

  // epilogue: accS[i][r] already holds the full row sum for q-row q4*4+r
  // (same D-layout row indexing as accO) -> normalize + store, no shuffles
  const int b = bh >> 4, h = bh & 15;
  #pragma unroll
  for (int i = 0; i < 2; ++i) {
    #pragma unroll
    for (int r = 0; r < 4; ++r) {
      const float invr = 1.f / accS[i][r];
      const int row = q0 + w * 32 + i * 16 + q4 * 4 + r;
      #pragma unroll
      for (int jd = 0; jd < 4; ++jd)
        o[((size_t)(b * SEQ + row)) * DIM + h * HD + jd * 16 + ln] = f2bf(accO[i][jd][r] * invr);
    }
  }
}

// ---------- launch ----------
extern "C" void kernel_launch(void* const* d_in, const int* in_sizes, int n_in,
                              void* d_out, int out_size, void* d_ws, size_t ws_size,
                              hipStream_t stream) {
  const float* x     = (const float*)d_in[0];   // [2,2048,1024]
  const float* Wqkv  = (const float*)d_in[1];   // [3072,1024]
  const float* bqkv  = (const float*)d_in[2];   // [3072]
  const float* Wout  = (const float*)d_in[3];   // [1024,1024]
  const float* bout  = (const float*)d_in[4];   // [1024]
  float* out = (float*)d_out;

  unsigned short* ws = (unsigned short*)d_ws;
  unsigned short* x_bf    = ws;
  unsigned short* wqkv_bf = x_bf    + (size_t)TOKENS * DIM;
  unsigned short* wout_bf = wqkv_bf + (size_t)3 * DIM * DIM;
  unsigned short* q_ws    = wout_bf + (size_t)DIM * DIM;
  unsigned short* k_ws    = q_ws    + (size_t)TOKENS * DIM;
  unsigned short* v_ws    = k_ws    + (size_t)TOKENS * DIM;    // transposed [bh][d][n]
  unsigned short* ao_ws   = v_ws    + (size_t)TOKENS * DIM;

  // fused cast (one launch)
  {
    const int n4 = N4_X + N4_WQ + N4_WO;   // 2,097,152 -> 8192 blocks
    mhsa_cast_all<<<n4 / 256, 256, 0, stream>>>(x, Wqkv, Wout, x_bf, wqkv_bf, wout_bf);
  }

  // QKV projection + scatter (V transposed, Q pre-scaled)
  {
    dim3 grid(3 * DIM / 128, TOKENS / 128);   // (24, 32) = 768 blocks = 3/CU, one round
    mhsa_gemm_qkv<<<grid, 256, 0, stream>>>(x_bf, wqkv_bf, bqkv, q_ws, k_ws, v_ws);
  }

  // fused attention
  {
    dim3 grid(SEQ / 128, BATCH * HEADS);      // (16, 32), 256 threads
    mhsa_attn<<<grid, 256, 0, stream>>>(q_ws, k_ws, v_ws, ao_ws);
  }

  // output projection
  {
    dim3 grid(DIM / 128, TOKENS / 64);        // (8, 64) = 512 blocks
    mhsa_gemm_out<<<grid, 256, 0, stream>>>(ao_ws, wout_bf, bout, out);
  }
}

// Round 12
// 179.339 us; speedup vs baseline: 1.1354x; 1.0124x over previous
//
#include <hip/hip_runtime.h>
#include <stdint.h>
#include <stddef.h>

typedef __attribute__((ext_vector_type(4))) float  f32x4;
typedef __attribute__((ext_vector_type(8))) short  s16x8;
typedef __attribute__((ext_vector_type(4))) float  float4v;
typedef __attribute__((ext_vector_type(4))) unsigned short u16x4;
typedef __attribute__((ext_vector_type(2))) unsigned int   u32x2;

#define DIM    1024
#define HEADS  16
#define HD     64
#define SEQ    2048
#define BATCH  2
#define TOKENS (BATCH * SEQ)   // 4096

// 0.125 (1/sqrt(64)) * log2(e): folded into Q so softmax uses exp2 directly
#define QSCALE 0.18033688011112042f

// ---------- helpers ----------
__device__ __forceinline__ unsigned short f2bf(float f) {
  union { float f; uint32_t u; } x; x.f = f;
  uint32_t r = x.u + 0x7fffu + ((x.u >> 16) & 1u);   // RNE
  return (unsigned short)(r >> 16);
}

__device__ __forceinline__ float fast_exp2(float x) {
#if __has_builtin(__builtin_amdgcn_exp2f)
  return __builtin_amdgcn_exp2f(x);
#else
  return exp2f(x);
#endif
}

// pack high-16s of two fp32 into one dword: (hi & 0xffff0000) | (lo >> 16)
__device__ __forceinline__ uint32_t pack_bf16_trunc(uint32_t lo, uint32_t hi) {
#if __has_builtin(__builtin_amdgcn_perm)
  return __builtin_amdgcn_perm(hi, lo, 0x07060302u);
#else
  return (hi & 0xffff0000u) | (lo >> 16);
#endif
}

// async global->LDS, 16 B per lane; lds dest = base + lane*16 (wave-uniform base)
__device__ __forceinline__ void stage16(const unsigned short* gp, unsigned short* lp) {
#if __has_builtin(__builtin_amdgcn_global_load_lds)
  __builtin_amdgcn_global_load_lds((const __attribute__((address_space(1))) void*)gp,
                                   (__attribute__((address_space(3))) void*)lp, 16, 0, 0);
#else
  *(s16x8*)(lp + (threadIdx.x & 63) * 8) = *(const s16x8*)gp;
#endif
}

// ---------- fused cast fp32 -> bf16 (x, W_qkv, W_out in one launch) ----------
#define N4_X  (TOKENS * DIM / 4)
#define N4_WQ (3 * DIM * DIM / 4)
#define N4_WO (DIM * DIM / 4)
__global__ __launch_bounds__(256) void mhsa_cast_all(const float* __restrict__ x,
    const float* __restrict__ wq, const float* __restrict__ wo,
    unsigned short* __restrict__ xb, unsigned short* __restrict__ wqb,
    unsigned short* __restrict__ wob) {
  int i = blockIdx.x * 256 + threadIdx.x;
  const float* src; unsigned short* dst; int off;
  if (i < N4_X)              { src = x;  dst = xb;  off = i; }
  else if (i < N4_X + N4_WQ) { src = wq; dst = wqb; off = i - N4_X; }
  else                       { src = wo; dst = wob; off = i - (N4_X + N4_WQ); }
  float4v f = ((const float4v*)src)[off];
  u16x4 o;
  o.x = f2bf(f.x); o.y = f2bf(f.y); o.z = f2bf(f.z); o.w = f2bf(f.w);
  ((u16x4*)dst)[off] = o;
}

// ================= GEMM core v3 =================
// BK=32, dbuf, 1 barrier/iter, XOR-swizzled 16B chunks, 3 blocks/CU.
// T1: XCD-chunked block swizzle -- co-locate blocks sharing an A-panel on one XCD.

// ---------- QKV GEMM (operand-swapped): C^T layout, packed epilogue ----------
__global__ __launch_bounds__(256, 3) void mhsa_gemm_qkv(const unsigned short* __restrict__ A,
    const unsigned short* __restrict__ Bw, const float* __restrict__ bias,
    unsigned short* __restrict__ qws, unsigned short* __restrict__ kws,
    unsigned short* __restrict__ vws) {
  __shared__ unsigned short As[2][128 * 32];
  __shared__ unsigned short Bs[2][128 * 32];
  const int t = threadIdx.x;
  const int w = t >> 6, l = t & 63;
  const int wm = w >> 1, wn = w & 1;
  // XCD swizzle: grid (24,32), 768 = 8 XCDs x 96. c = lin%8 -> XCD; each XCD gets
  // 4 complete row-panels (by' in {4c..4c+3}); all 24 col-blocks of a panel share it.
  const int lin = blockIdx.y * 24 + blockIdx.x;
  const int xc = lin & 7, j = lin >> 3;               // j in [0,96)
  const int rowBase = (xc * 4 + j / 24) * 128;        // tokens
  const int colBase = (j % 24) * 128;                 // e
  const int fr = l & 15, q4 = l >> 4, ln = l & 15;
  const int srow = l >> 2;                       // staging row within slab
  const int scol = ((l & 3) ^ (srow & 3)) * 8;   // swizzled global column

  f32x4 zero = {0.f, 0.f, 0.f, 0.f};
  f32x4 acc[4][4];   // [a=e-tile][b=token-tile]
  #pragma unroll
  for (int a = 0; a < 4; ++a)
    #pragma unroll
    for (int b = 0; b < 4; ++b) acc[a][b] = zero;

  #pragma unroll
  for (int it = 0; it < 2; ++it) {
    const int c = w * 2 + it;
    stage16(A  + (size_t)(rowBase + c * 16 + srow) * DIM + scol, &As[0][c * 512]);
    stage16(Bw + (size_t)(colBase + c * 16 + srow) * DIM + scol, &Bs[0][c * 512]);
  }
  __syncthreads();

  for (int kt = 0; kt < DIM / 32; ++kt) {
    const int cur = kt & 1, nxt = cur ^ 1;
    if (kt + 1 < DIM / 32) {
      const int k1 = (kt + 1) * 32;
      #pragma unroll
      for (int it = 0; it < 2; ++it) {
        const int c = w * 2 + it;
        stage16(A  + (size_t)(rowBase + c * 16 + srow) * DIM + k1 + scol, &As[nxt][c * 512]);
        stage16(Bw + (size_t)(colBase + c * 16 + srow) * DIM + k1 + scol, &Bs[nxt][c * 512]);
      }
    }
    s16x8 xf[4], wf[4];
    #pragma unroll
    for (int b = 0; b < 4; ++b)
      xf[b] = *(const s16x8*)&As[cur][(wm * 64 + b * 16 + fr) * 32 + ((q4 ^ (fr & 3)) * 8)];
    #pragma unroll
    for (int a = 0; a < 4; ++a)
      wf[a] = *(const s16x8*)&Bs[cur][(wn * 64 + a * 16 + fr) * 32 + ((q4 ^ (fr & 3)) * 8)];
    #pragma unroll
    for (int a = 0; a < 4; ++a)
      #pragma unroll
      for (int b = 0; b < 4; ++b)
        acc[a][b] = __builtin_amdgcn_mfma_f32_16x16x32_bf16(wf[a], xf[b], acc[a][b], 0, 0, 0);
    __syncthreads();
  }

  const int which = colBase >> 10;   // 0=Q 1=K 2=V (block never straddles)
  const float sc = (which == 0) ? QSCALE : 1.0f;
  unsigned short* dst = (which == 0) ? qws : ((which == 1) ? kws : vws);

  #pragma unroll
  for (int a = 0; a < 4; ++a) {
    const int e0 = colBase + wn * 64 + a * 16 + q4 * 4;  // 4-aligned, 4 consecutive e
    const float4v bs4 = *(const float4v*)&bias[e0];
    const int rr0 = e0 & 1023;
    const int h = rr0 >> 6, d0 = rr0 & 63;               // d0..d0+3 within one head
    #pragma unroll
    for (int b = 0; b < 4; ++b) {
      const int tok = rowBase + wm * 64 + b * 16 + ln;
      const int bb = tok >> 11, n = tok & 2047;
      if (which != 2) {
        u16x4 pk;
        #pragma unroll
        for (int r = 0; r < 4; ++r) pk[r] = f2bf((acc[a][b][r] + bs4[r]) * sc);
        *(u16x4*)&dst[(((size_t)(bb * HEADS + h)) * SEQ + n) * HD + d0] = pk;
      } else {
        #pragma unroll
        for (int r = 0; r < 4; ++r)
          dst[(((size_t)(bb * HEADS + h)) * HD + d0 + r) * SEQ + n] =
              f2bf(acc[a][b][r] + bs4[r]);
      }
    }
  }
}

// ---------- Output GEMM (operand-swapped): 64x128 tiles, float4 epilogue ----------
__global__ __launch_bounds__(256, 3) void mhsa_gemm_out(const unsigned short* __restrict__ A,
    const unsigned short* __restrict__ Bw, const float* __restrict__ bias,
    float* __restrict__ out) {
  __shared__ unsigned short As[2][64 * 32];
  __shared__ unsigned short Bs[2][128 * 32];
  const int t = threadIdx.x;
  const int w = t >> 6, l = t & 63;
  const int wm = w >> 1, wn = w & 1;
  // XCD swizzle: grid (8,64), 512 = 8 x 64; each XCD gets 8 row-panels.
  const int lin = blockIdx.y * 8 + blockIdx.x;
  const int xc = lin & 7, j = lin >> 3;               // j in [0,64)
  const int rowBase = (xc * 8 + (j >> 3)) * 64;       // tokens
  const int colBase = (j & 7) * 128;                  // e
  const int fr = l & 15, q4 = l >> 4, ln = l & 15;
  const int srow = l >> 2;
  const int scol = ((l & 3) ^ (srow & 3)) * 8;

  f32x4 zero = {0.f, 0.f, 0.f, 0.f};
  f32x4 acc[4][2];   // [a=e-tile][b=token-tile]
  #pragma unroll
  for (int a = 0; a < 4; ++a)
    #pragma unroll
    for (int b = 0; b < 2; ++b) acc[a][b] = zero;

  #pragma unroll
  for (int it = 0; it < 3; ++it) {
    const int s = w * 3 + it;
    if (s < 4) stage16(A  + (size_t)(rowBase + s * 16 + srow) * DIM + scol, &As[0][s * 512]);
    else       stage16(Bw + (size_t)(colBase + (s - 4) * 16 + srow) * DIM + scol, &Bs[0][(s - 4) * 512]);
  }
  __syncthreads();

  for (int kt = 0; kt < DIM / 32; ++kt) {
    const int cur = kt & 1, nxt = cur ^ 1;
    if (kt + 1 < DIM / 32) {
      const int k1 = (kt + 1) * 32;
      #pragma unroll
      for (int it = 0; it < 3; ++it) {
        const int s = w * 3 + it;
        if (s < 4) stage16(A  + (size_t)(rowBase + s * 16 + srow) * DIM + k1 + scol, &As[nxt][s * 512]);
        else       stage16(Bw + (size_t)(colBase + (s - 4) * 16 + srow) * DIM + k1 + scol, &Bs[nxt][(s - 4) * 512]);
      }
    }
    s16x8 xf[2], wf[4];
    #pragma unroll
    for (int b = 0; b < 2; ++b)
      xf[b] = *(const s16x8*)&As[cur][(wm * 32 + b * 16 + fr) * 32 + ((q4 ^ (fr & 3)) * 8)];
    #pragma unroll
    for (int a = 0; a < 4; ++a)
      wf[a] = *(const s16x8*)&Bs[cur][(wn * 64 + a * 16 + fr) * 32 + ((q4 ^ (fr & 3)) * 8)];
    #pragma unroll
    for (int a = 0; a < 4; ++a)
      #pragma unroll
      for (int b = 0; b < 2; ++b)
        acc[a][b] = __builtin_amdgcn_mfma_f32_16x16x32_bf16(wf[a], xf[b], acc[a][b], 0, 0, 0);
    __syncthreads();
  }

  #pragma unroll
  for (int a = 0; a < 4; ++a) {
    const int e0 = colBase + wn * 64 + a * 16 + q4 * 4;
    const float4v bs4 = *(const float4v*)&bias[e0];
    #pragma unroll
    for (int b = 0; b < 2; ++b) {
      const int tok = rowBase + wm * 32 + b * 16 + ln;
      float4v v;
      #pragma unroll
      for (int r = 0; r < 4; ++r) v[r] = acc[a][b][r] + bs4[r];
      *(float4v*)&out[(size_t)tok * DIM + e0] = v;
    }
  }
}

// ---------- Flash attention v13 (final): v7 schedule + XCD-aware bh swizzle ----------
// 256 threads (4 waves x 32 q-rows), K/V tiles 64, XOR-swizzled staging, P via LDS
// round-trip, rowsum on the matrix pipe (P x ones), setprio around MFMA clusters.
// T1: blocks remapped so all 16 q-tiles of one bh land on ONE XCD (K/V 512KB
// L2-resident per bh; 4 bh = 2MB per XCD L2). c=lin%8 picks XCD; bh = c*4 + (m>>4).
// Session verdict: structural departures (reg-K/V, counted vmcnt, 32x32 in-reg P,
// 8-wave, V-from-global) all lost to this schedule. This is the proven optimum.
__global__ __launch_bounds__(256, 2) void mhsa_attn(const unsigned short* __restrict__ q,
    const unsigned short* __restrict__ k, const unsigned short* __restrict__ vt,
    unsigned short* __restrict__ o) {
  __shared__ unsigned short QPs[4 * 32 * 72];   // per-wave 2304: Q staged (2048) then P (32x72)
  __shared__ unsigned short Ks[2][64 * 64];     // dbuf K tile (staged 2 ahead)
  __shared__ unsigned short Vs[2][64 * 64];     // dbuf V^T tile (staged 1 ahead)
  const int t = threadIdx.x, w = t >> 6, l = t & 63;
  const int q4 = l >> 4, ln = l & 15;
  // XCD swizzle: grid (16,32). lin = by*16+bx; XCD = lin%8 gets bh in {4c..4c+3}.
  const int lin = blockIdx.y * 16 + blockIdx.x;
  const int xc = lin & 7, m = lin >> 3;          // m in [0,64)
  const int bh = xc * 4 + (m >> 4);
  const int q0 = (m & 15) * 128;
  const unsigned short* qb  = q  + (size_t)bh * SEQ * HD;
  const unsigned short* kb  = k  + (size_t)bh * SEQ * HD;
  const unsigned short* vtb = vt + (size_t)bh * HD * SEQ;

  const int srow = l >> 3;
  const int scol = ((l & 7) ^ srow) * 8;

  unsigned short* Pw = &QPs[w * (32 * 72)];

  // bf16 1.0 x8 for the row-sum MFMA B operand
  const s16x8 vones = {(short)0x3F80, (short)0x3F80, (short)0x3F80, (short)0x3F80,
                       (short)0x3F80, (short)0x3F80, (short)0x3F80, (short)0x3F80};

  // prologue staging: Q (wave-local region), K_0, V_0, K_1
  #pragma unroll
  for (int it = 0; it < 4; ++it)
    stage16(qb + (size_t)(q0 + w * 32 + it * 8 + srow) * HD + scol, &Pw[it * 512]);
  #pragma unroll
  for (int it = 0; it < 2; ++it) {
    const int c = w + it * 4;
    stage16(kb  + (size_t)(c * 8 + srow) * HD + scol,        &Ks[0][c * 512]);
    stage16(vtb + (size_t)(c * 8 + srow) * SEQ + scol,       &Vs[0][c * 512]);
    stage16(kb  + (size_t)(64 + c * 8 + srow) * HD + scol,   &Ks[1][c * 512]);
  }
  __syncthreads();   // publishes Q + K_0 + V_0 + K_1

  // hoist Q fragments; Pw region then reused for P
  s16x8 aq[2][2];
  #pragma unroll
  for (int i = 0; i < 2; ++i)
    #pragma unroll
    for (int kk = 0; kk < 2; ++kk)
      aq[i][kk] = *(const s16x8*)&Pw[(i * 16 + ln) * 64 + (((kk * 4 + q4) ^ (ln & 7)) * 8)];

  f32x4 zero = {0.f, 0.f, 0.f, 0.f};
  f32x4 accO[2][4];
  f32x4 accS[2] = {zero, zero};   // per-row sums of P (via MFMA with ones)
  #pragma unroll
  for (int i = 0; i < 2; ++i)
    #pragma unroll
    for (int jd = 0; jd < 4; ++jd) accO[i][jd] = zero;

  // prologue compute: S_0 from Ks[0], exp, write P_0
  {
    f32x4 St[4][2];
    #pragma unroll
    for (int jb = 0; jb < 4; ++jb)
      #pragma unroll
      for (int i = 0; i < 2; ++i) St[jb][i] = zero;
    __builtin_amdgcn_s_setprio(1);
    #pragma unroll
    for (int jb = 0; jb < 4; ++jb) {
      s16x8 ak0 = *(const s16x8*)&Ks[0][(jb * 16 + ln) * 64 + ((q4 ^ (ln & 7)) * 8)];
      s16x8 ak1 = *(const s16x8*)&Ks[0][(jb * 16 + ln) * 64 + (((4 + q4) ^ (ln & 7)) * 8)];
      #pragma unroll
      for (int i = 0; i < 2; ++i) {
        St[jb][i] = __builtin_amdgcn_mfma_f32_16x16x32_bf16(ak0, aq[i][0], St[jb][i], 0, 0, 0);
        St[jb][i] = __builtin_amdgcn_mfma_f32_16x16x32_bf16(ak1, aq[i][1], St[jb][i], 0, 0, 0);
      }
    }
    __builtin_amdgcn_s_setprio(0);
    #pragma unroll
    for (int i = 0; i < 2; ++i)
      #pragma unroll
      for (int jb = 0; jb < 4; ++jb) {
        uint32_t u0 = __float_as_uint(fast_exp2(St[jb][i][0]));
        uint32_t u1 = __float_as_uint(fast_exp2(St[jb][i][1]));
        uint32_t u2 = __float_as_uint(fast_exp2(St[jb][i][2]));
        uint32_t u3 = __float_as_uint(fast_exp2(St[jb][i][3]));
        u32x2 pk;
        pk.x = pack_bf16_trunc(u0, u1);
        pk.y = pack_bf16_trunc(u2, u3);
        *(u32x2*)&Pw[(i * 16 + ln) * 72 + jb * 16 + q4 * 4] = pk;
      }
  }
  __syncthreads();   // drains K_0 frag reads before loop iter 0 overwrites Ks[0]

  const int NT = SEQ / 64;   // 32
  for (int jt = 0; jt < NT; ++jt) {
    const int cur = jt & 1, nxt = cur ^ 1;
    // stage K_{jt+2} into slot cur (K_jt's reads drained at previous barrier);
    // stage V_{jt+1} into slot nxt (V_jt being read from slot cur)
    if (jt + 2 < NT) {
      const int j2 = (jt + 2) * 64;
      #pragma unroll
      for (int it = 0; it < 2; ++it) {
        const int c = w + it * 4;
        stage16(kb + (size_t)(j2 + c * 8 + srow) * HD + scol, &Ks[cur][c * 512]);
      }
    }
    if (jt + 1 < NT) {
      const int j1 = (jt + 1) * 64;
      #pragma unroll
      for (int it = 0; it < 2; ++it) {
        const int c = w + it * 4;
        stage16(vtb + (size_t)(c * 8 + srow) * SEQ + j1 + scol, &Vs[nxt][c * 512]);
      }
    }

    // ---- stream A: PV_jt from P_jt (written last iter) and V_jt ----
    s16x8 ap[2][2];
    #pragma unroll
    for (int i = 0; i < 2; ++i)
      #pragma unroll
      for (int kk = 0; kk < 2; ++kk)
        ap[i][kk] = *(const s16x8*)&Pw[(i * 16 + ln) * 72 + kk * 32 + q4 * 8];

    // row-sum MFMAs: accS[i] += P x ones (sums exactly the stored bf16 P values)
    __builtin_amdgcn_s_setprio(1);
    #pragma unroll
    for (int i = 0; i < 2; ++i) {
      accS[i] = __builtin_amdgcn_mfma_f32_16x16x32_bf16(ap[i][0], vones, accS[i], 0, 0, 0);
      accS[i] = __builtin_amdgcn_mfma_f32_16x16x32_bf16(ap[i][1], vones, accS[i], 0, 0, 0);
    }
    __builtin_amdgcn_s_setprio(0);

    // ---- stream B: S_{jt+1} from K_{jt+1} (slot nxt) ----
    if (jt + 1 < NT) {
      f32x4 St[4][2];
      #pragma unroll
      for (int jb = 0; jb < 4; ++jb)
        #pragma unroll
        for (int i = 0; i < 2; ++i) St[jb][i] = zero;
      __builtin_amdgcn_s_setprio(1);
      #pragma unroll
      for (int jb = 0; jb < 4; ++jb) {
        s16x8 ak0 = *(const s16x8*)&Ks[nxt][(jb * 16 + ln) * 64 + ((q4 ^ (ln & 7)) * 8)];
        s16x8 ak1 = *(const s16x8*)&Ks[nxt][(jb * 16 + ln) * 64 + (((4 + q4) ^ (ln & 7)) * 8)];
        #pragma unroll
        for (int i = 0; i < 2; ++i) {
          St[jb][i] = __builtin_amdgcn_mfma_f32_16x16x32_bf16(ak0, aq[i][0], St[jb][i], 0, 0, 0);
          St[jb][i] = __builtin_amdgcn_mfma_f32_16x16x32_bf16(ak1, aq[i][1], St[jb][i], 0, 0, 0);
        }
      }

      // PV_jt MFMAs (independent of St chain; fills MFMA pipe while exp runs)
      #pragma unroll
      for (int jd = 0; jd < 4; ++jd) {
        s16x8 bv0 = *(const s16x8*)&Vs[cur][(jd * 16 + ln) * 64 + ((q4 ^ (ln & 7)) * 8)];
        s16x8 bv1 = *(const s16x8*)&Vs[cur][(jd * 16 + ln) * 64 + (((4 + q4) ^ (ln & 7)) * 8)];
        #pragma unroll
        for (int i = 0; i < 2; ++i) {
          accO[i][jd] = __builtin_amdgcn_mfma_f32_16x16x32_bf16(ap[i][0], bv0, accO[i][jd], 0, 0, 0);
          accO[i][jd] = __builtin_amdgcn_mfma_f32_16x16x32_bf16(ap[i][1], bv1, accO[i][jd], 0, 0, 0);
        }
      }
      __builtin_amdgcn_s_setprio(0);

      // exp -> pack -> write P_{jt+1} (anti-dep on ap reads keeps order vs Pw)
      #pragma unroll
      for (int i = 0; i < 2; ++i)
        #pragma unroll
        for (int jb = 0; jb < 4; ++jb) {
          uint32_t u0 = __float_as_uint(fast_exp2(St[jb][i][0]));
          uint32_t u1 = __float_as_uint(fast_exp2(St[jb][i][1]));
          uint32_t u2 = __float_as_uint(fast_exp2(St[jb][i][2]));
          uint32_t u3 = __float_as_uint(fast_exp2(St[jb][i][3]));
          u32x2 pk;
          pk.x = pack_bf16_trunc(u0, u1);
          pk.y = pack_bf16_trunc(u2, u3);
          *(u32x2*)&Pw[(i * 16 + ln) * 72 + jb * 16 + q4 * 4] = pk;
        }
    } else {
      // last iter: only PV
      __builtin_amdgcn_s_setprio(1);
      #pragma unroll
      for (int jd = 0; jd < 4; ++jd) {
        s16x8 bv0 = *(const s16x8*)&Vs[cur][(jd * 16 + ln) * 64 + ((q4 ^ (ln & 7)) * 8)];
        s16x8 bv1 = *(const s16x8*)&Vs[cur][(jd * 16 + ln) * 64 + (((4 + q4) ^ (ln & 7)) * 8)];
        #pragma unroll
        for (int i = 0; i < 2; ++i) {
          accO[i][jd] = __builtin_amdgcn_mfma_f32_16x16x32_bf16(ap[i][0], bv0, accO[i][jd], 0, 0, 0);
          accO[i][jd] = __builtin_amdgcn_mfma_f32_16x16x32_bf16(ap[i][1], bv1, accO[i][jd], 0, 0, 0);
        }
      }
      __builtin_amdgcn_s_setprio(0);
    }

    __syncthreads();   // publishes staging; drains cur-slot reads before reuse
  }

  // epilogue: accS[i][r] already holds the full row sum for q-row q4*4+r
  // (same D-layout row indexing as accO) -> normalize + store, no shuffles
  const int b = bh >> 4, h = bh & 15;
  #pragma unroll
  for (int i = 0; i < 2; ++i) {
    #pragma unroll
    for (int r = 0; r < 4; ++r) {
      const float invr = 1.f / accS[i][r];
      const int row = q0 + w * 32 + i * 16 + q4 * 4 + r;
      #pragma unroll
      for (int jd = 0; jd < 4; ++jd)
        o[((size_t)(b * SEQ + row)) * DIM + h * HD + jd * 16 + ln] = f2bf(accO[i][jd][r] * invr);
    }
  }
}

// ---------- launch ----------
extern "C" void kernel_launch(void* const* d_in, const int* in_sizes, int n_in,
                              void* d_out, int out_size, void* d_ws, size_t ws_size,
                              hipStream_t stream) {
  const float* x     = (const float*)d_in[0];   // [2,2048,1024]
  const float* Wqkv  = (const float*)d_in[1];   // [3072,1024]
  const float* bqkv  = (const float*)d_in[2];   // [3072]
  const float* Wout  = (const float*)d_in[3];   // [1024,1024]
  const float* bout  = (const float*)d_in[4];   // [1024]
  float* out = (float*)d_out;

  unsigned short* ws = (unsigned short*)d_ws;
  unsigned short* x_bf    = ws;
  unsigned short* wqkv_bf = x_bf    + (size_t)TOKENS * DIM;
  unsigned short* wout_bf = wqkv_bf + (size_t)3 * DIM * DIM;
  unsigned short* q_ws    = wout_bf + (size_t)DIM * DIM;
  unsigned short* k_ws    = q_ws    + (size_t)TOKENS * DIM;
  unsigned short* v_ws    = k_ws    + (size_t)TOKENS * DIM;    // transposed [bh][d][n]
  unsigned short* ao_ws   = v_ws    + (size_t)TOKENS * DIM;

  // fused cast (one launch)
  {
    const int n4 = N4_X + N4_WQ + N4_WO;   // 2,097,152 -> 8192 blocks
    mhsa_cast_all<<<n4 / 256, 256, 0, stream>>>(x, Wqkv, Wout, x_bf, wqkv_bf, wout_bf);
  }

  // QKV projection + scatter (V transposed, Q pre-scaled)
  {
    dim3 grid(3 * DIM / 128, TOKENS / 128);   // (24, 32) = 768 blocks = 3/CU, one round
    mhsa_gemm_qkv<<<grid, 256, 0, stream>>>(x_bf, wqkv_bf, bqkv, q_ws, k_ws, v_ws);
  }

  // fused attention
  {
    dim3 grid(SEQ / 128, BATCH * HEADS);      // (16, 32), 256 threads
    mhsa_attn<<<grid, 256, 0, stream>>>(q_ws, k_ws, v_ws, ao_ws);
  }

  // output projection
  {
    dim3 grid(DIM / 128, TOKENS / 64);        // (8, 64) = 512 blocks
    mhsa_gemm_out<<<grid, 256, 0, stream>>>(ao_ws, wout_bf, bout, out);
  }
}